// Round 20
// baseline (51.413 us; speedup 1.0000x reference)
//
#include <hip/hip_runtime.h>
#include <hip/hip_bf16.h>
#include <stdint.h>

#define NB 4096
#define ND 1024

typedef __attribute__((ext_vector_type(4))) float f32x4;
typedef __attribute__((ext_vector_type(2))) long i64x2;   // 16B = two fp8 MFMA operands

// ---------------------------------------------------------------------------
// prep: row-normalize, quantize to fp8 e4m3 (OCP), write SUPERFRAG-ORDERED zq,
// pack label key. (byte-identical to R14 -- passed, absmax 0.0)
// ---------------------------------------------------------------------------
__global__ __launch_bounds__(256) void prep_kernel(
    const float* __restrict__ emb, const int* __restrict__ labels,
    unsigned char* __restrict__ zq, int* __restrict__ keys)
{
    const int wid = threadIdx.x >> 6, lane = threadIdx.x & 63;
    const int row = blockIdx.x * 4 + wid;
    const float4* src = (const float4*)(emb + (size_t)row * ND) + lane * 4;
    float4 v[4];
    float ss = 0.0f;
    #pragma unroll
    for (int j = 0; j < 4; ++j) {
        v[j] = src[j];
        ss += v[j].x * v[j].x + v[j].y * v[j].y + v[j].z * v[j].z + v[j].w * v[j].w;
    }
    #pragma unroll
    for (int o = 1; o < 64; o <<= 1) ss += __shfl_xor(ss, o);
    const float inv = 1.0f / fmaxf(sqrtf(ss), 1e-12f);

    int p0 = 0, p1 = 0, p2 = 0, p3 = 0;
    p0 = __builtin_amdgcn_cvt_pk_fp8_f32(v[0].x * inv, v[0].y * inv, p0, false);
    p0 = __builtin_amdgcn_cvt_pk_fp8_f32(v[0].z * inv, v[0].w * inv, p0, true);
    p1 = __builtin_amdgcn_cvt_pk_fp8_f32(v[1].x * inv, v[1].y * inv, p1, false);
    p1 = __builtin_amdgcn_cvt_pk_fp8_f32(v[1].z * inv, v[1].w * inv, p1, true);
    p2 = __builtin_amdgcn_cvt_pk_fp8_f32(v[2].x * inv, v[2].y * inv, p2, false);
    p2 = __builtin_amdgcn_cvt_pk_fp8_f32(v[2].z * inv, v[2].w * inv, p2, true);
    p3 = __builtin_amdgcn_cvt_pk_fp8_f32(v[3].x * inv, v[3].y * inv, p3, false);
    p3 = __builtin_amdgcn_cvt_pk_fp8_f32(v[3].z * inv, v[3].w * inv, p3, true);

    const int sf  = (row >> 4) * 16 + (lane >> 2);
    const int sel = (lane >> 1) & 1;
    const int c0  = (lane & 1) * 2;
    const int L0  = (row & 15) + 16 * c0;
    unsigned char* d = zq + (size_t)sf * 1024;
    int2 w01; w01.x = p0; w01.y = p1;   // k+0..7  -> chunk c0
    int2 w23; w23.x = p2; w23.y = p3;   // k+8..15 -> chunk c0+1
    *(int2*)(d + L0 * 16 + sel * 8)        = w01;
    *(int2*)(d + (L0 + 16) * 16 + sel * 8) = w23;

    if (lane == 0) {
        const int* lr = labels + row * 4;
        keys[row] = ((lr[3] & 7) << 24) | ((lr[0] & 7) << 16) |
                    ((lr[1] & 7) << 8)  |  (lr[2] & 7);
    }
}

// ---------------------------------------------------------------------------
// simtile (R20): R14's triangle/epilogue with REGISTER-STAGED LDS DEDUP.
// R14 issued 2x redundant bytes (both wm-waves load the same A frags, both
// wn-waves the same B frags): 64 KB issued / 32 KB unique per CU-step-pair
// at the measured ~15.6 B/cy/CU issued-byte cap. Here each wave loads only
// its unique 4 superfrags (4 KB) -> ds_write into a double-buffered 16-frag
// pool -> one barrier/step -> ds_read the 8 operand frags. All LDS accesses
// are lane-contiguous 1KB (conflict-free). Loads for t+1 issue before the
// MFMAs of t. NOT global_load_lds (that pipe walled at 8.5 B/cy, R5-R9) --
// plain loads to regs + ds_write (T14). If the cap is on issued bytes this
// halves step time; if on unique L2-side bytes it is neutral -- decisive
// either way. Prep/rowreduce/final byte-identical to R14.
// ---------------------------------------------------------------------------
__global__ __launch_bounds__(256, 2) void simtile_kernel(
    const unsigned char* __restrict__ zq, const int* __restrict__ keys,
    float* __restrict__ partials)
{
    const int b = blockIdx.x;
    const int p = (b & 7) * 66 + (b >> 3);   // XCD-contiguous triangle index
    int r = (int)((sqrtf(8.0f * p + 1.0f) - 1.0f) * 0.5f);
    while ((r + 1) * (r + 2) / 2 <= p) ++r;
    while (r * (r + 1) / 2 > p) --r;
    const int bi = p - r * (r + 1) / 2;      // I panel (rows of D), bi <= bj
    const int bj = r;                        // J panel (cols of D)
    const int I0 = bi * 128, J0 = bj * 128;
    const bool offdiag = (bi != bj);
    const bool diag = !offdiag;

    const int tid = threadIdx.x;
    const int lane = tid & 63, w = tid >> 6;          // 4 waves
    const int llo = lane & 15, lhi = lane >> 4;
    const int wm = w >> 1, wn = w & 1;                // 2 x 2 wave grid

    __shared__ __align__(16) unsigned char sfb[2][16][1024];   // 32 KB dbuf pool
    __shared__ float epiA[2][128][4];                 // 4 KB
    __shared__ float epiB[2][128][4];                 // 4 KB
    __shared__ int keyI[128];
    __shared__ int keyJ[128];

    if (tid < 128) {
        keyI[tid] = keys[I0 + tid];
        keyJ[tid] = keys[J0 + tid];
    }

    // unique-load assignment: wave w owns pool frags w*4..w*4+3.
    // frags 0..7 = A panel rowtiles (bi*8 + f); frags 8..15 = B rowtiles (bj*8 + f-8).
    const unsigned char* gpanel = (w < 2)
        ? (zq + (size_t)(bi * 8 + w * 4) * 16384 + lane * 16)
        : (zq + (size_t)(bj * 8 + (w - 2) * 4) * 16384 + lane * 16);

    i64x2 stg[4];
    #define GLOADU(T)                                                              \
        do {                                                                       \
            _Pragma("unroll")                                                      \
            for (int q = 0; q < 4; ++q)                                            \
                stg[q] = *(const i64x2*)(gpanel + (size_t)q * 16384 + (T) * 1024); \
        } while (0)
    #define DSWRITE(B)                                                             \
        do {                                                                       \
            _Pragma("unroll")                                                      \
            for (int q = 0; q < 4; ++q)                                            \
                *(i64x2*)(&sfb[B][w * 4 + q][lane * 16]) = stg[q];                 \
        } while (0)

    f32x4 acc[4][4];
    #pragma unroll
    for (int m = 0; m < 4; ++m)
        #pragma unroll
        for (int n = 0; n < 4; ++n)
            acc[m][n] = (f32x4){0.f, 0.f, 0.f, 0.f};

    GLOADU(0);
    DSWRITE(0);
    __syncthreads();

    #pragma unroll 1
    for (int t = 0; t < 16; ++t) {
        const int buf = t & 1;
        i64x2 a[4], bb[4];
        #pragma unroll
        for (int m = 0; m < 4; ++m)
            a[m] = *(const i64x2*)(&sfb[buf][wm * 4 + m][lane * 16]);
        #pragma unroll
        for (int n = 0; n < 4; ++n)
            bb[n] = *(const i64x2*)(&sfb[buf][8 + wn * 4 + n][lane * 16]);
        if (t < 15) GLOADU(t + 1);            // in flight under the MFMAs
        #pragma unroll
        for (int m = 0; m < 4; ++m)
            #pragma unroll
            for (int n = 0; n < 4; ++n) {
                acc[m][n] = __builtin_amdgcn_mfma_f32_16x16x32_fp8_fp8(
                    a[m][0], bb[n][0], acc[m][n], 0, 0, 0);
                acc[m][n] = __builtin_amdgcn_mfma_f32_16x16x32_fp8_fp8(
                    a[m][1], bb[n][1], acc[m][n], 0, 0, 0);
            }
        if (t < 15) DSWRITE(buf ^ 1);         // write NEXT step's buffer
        __syncthreads();
    }
    #undef GLOADU
    #undef DSWRITE

    // -------- dual-sided epilogue (R14) ------------------------------------
    int kJ[4], tcol[4];
    #pragma unroll
    for (int n = 0; n < 4; ++n) {
        tcol[n] = wn * 64 + n * 16 + llo;
        kJ[n] = keyJ[tcol[n]];
    }

    float stB[4][4];
    #pragma unroll
    for (int n = 0; n < 4; ++n)
        #pragma unroll
        for (int s = 0; s < 4; ++s) stB[n][s] = 0.0f;

    #pragma unroll
    for (int m = 0; m < 4; ++m) {
        float stA[4][4];
        #pragma unroll
        for (int rr = 0; rr < 4; ++rr)
            #pragma unroll
            for (int s = 0; s < 4; ++s) stA[rr][s] = 0.0f;

        int kI[4], trow[4];
        #pragma unroll
        for (int rr = 0; rr < 4; ++rr) {
            trow[rr] = wm * 64 + m * 16 + lhi * 4 + rr;
            kI[rr] = keyI[trow[rr]];
        }
        #pragma unroll
        for (int n = 0; n < 4; ++n) {
            #pragma unroll
            for (int rr = 0; rr < 4; ++rr) {
                const float v = acc[m][n][rr] * 10.0f;
                const int x = kI[rr] ^ kJ[n];
                const float pen = (x & 0xFF000000) ? 1.0f : 0.0f;
                const float g = __expf(v - 10.0f - pen);
                if (!(diag && trow[rr] == tcol[n])) {
                    stA[rr][0] += g;           stB[n][0] += g;
                    if ((x & 0xFFFF0000) == 0) { stA[rr][1] += v; stB[n][1] += v; }
                    if ((x & 0xFFFFFF00) == 0) { stA[rr][2] += v; stB[n][2] += v; }
                    if (x == 0)                { stA[rr][3] += v; stB[n][3] += v; }
                }
            }
        }
        // side A: reduce over the 16 llo lanes (cols within wave)
        #pragma unroll
        for (int rr = 0; rr < 4; ++rr)
            #pragma unroll
            for (int s = 0; s < 4; ++s) {
                float vv = stA[rr][s];
                vv += __shfl_xor(vv, 1);
                vv += __shfl_xor(vv, 2);
                vv += __shfl_xor(vv, 4);
                vv += __shfl_xor(vv, 8);
                stA[rr][s] = vv;
            }
        if (llo == 0) {
            #pragma unroll
            for (int rr = 0; rr < 4; ++rr) {
                float4 o; o.x = stA[rr][0]; o.y = stA[rr][1]; o.z = stA[rr][2]; o.w = stA[rr][3];
                *(float4*)&epiA[wn][trow[rr]][0] = o;
            }
        }
    }
    // side B: reduce over the 4 lhi lane-groups (rows within wave)
    #pragma unroll
    for (int n = 0; n < 4; ++n)
        #pragma unroll
        for (int s = 0; s < 4; ++s) {
            float vv = stB[n][s];
            vv += __shfl_xor(vv, 16);
            vv += __shfl_xor(vv, 32);
            stB[n][s] = vv;
        }
    if (lhi == 0) {
        #pragma unroll
        for (int n = 0; n < 4; ++n) {
            float4 o; o.x = stB[n][0]; o.y = stB[n][1]; o.z = stB[n][2]; o.w = stB[n][3];
            *(float4*)&epiB[wm][tcol[n]][0] = o;
        }
    }
    __syncthreads();

    if (tid < 128) {
        const float4 a0 = *(const float4*)&epiA[0][tid][0];
        const float4 a1 = *(const float4*)&epiA[1][tid][0];
        float4 o; o.x = a0.x + a1.x; o.y = a0.y + a1.y; o.z = a0.z + a1.z; o.w = a0.w + a1.w;
        *(float4*)(partials + ((size_t)bj * NB + I0 + tid) * 4) = o;
        if (offdiag) {
            const float4 b0 = *(const float4*)&epiB[0][tid][0];
            const float4 b1 = *(const float4*)&epiB[1][tid][0];
            float4 q; q.x = b0.x + b1.x; q.y = b0.y + b1.y; q.z = b0.z + b1.z; q.w = b0.w + b1.w;
            *(float4*)(partials + ((size_t)bi * NB + J0 + tid) * 4) = q;
        }
    }
}

// ---------------------------------------------------------------------------
// row reduce: block-local LDS histogram of keys (counts), then sum {G,T1,T2,T3}
// over 32 coltiles, per-level per-row values, block-reduce to 6 sums.
// ---------------------------------------------------------------------------
__global__ __launch_bounds__(256) void rowreduce_kernel(
    const float* __restrict__ partials, const int* __restrict__ keys,
    float* __restrict__ blocksums)
{
    const int tid = threadIdx.x;
    const int row = blockIdx.x * 256 + tid;
    const int lane = tid & 63, wid = tid >> 6;

    __shared__ int h3[4096];
    __shared__ int h2[512];
    __shared__ int h1[64];

    for (int i = tid; i < 4096; i += 256) h3[i] = 0;
    __syncthreads();
    for (int i = tid; i < 4096; i += 256) {
        const int k = keys[i];
        const int i3 = (((((k >> 24) & 7) * 8 + ((k >> 16) & 7)) * 8 + ((k >> 8) & 7)) * 8) + (k & 7);
        atomicAdd(&h3[i3], 1);
    }
    __syncthreads();
    for (int i = tid; i < 512; i += 256) {
        int s = 0;
        #pragma unroll
        for (int j = 0; j < 8; ++j) s += h3[i * 8 + j];
        h2[i] = s;
    }
    __syncthreads();
    if (tid < 64) {
        int s = 0;
        #pragma unroll
        for (int j = 0; j < 8; ++j) s += h2[tid * 8 + j];
        h1[tid] = s;
    }
    __syncthreads();

    float G = 0.f, T1 = 0.f, T2 = 0.f, T3 = 0.f;
    for (int ct = 0; ct < 32; ++ct) {
        const float4 u = *(const float4*)(partials + ((size_t)ct * NB + row) * 4);
        G += u.x; T1 += u.y; T2 += u.z; T3 += u.w;
    }
    const float lg = logf(fmaxf(G, 1e-30f)) + 10.0f;   // = logZ + m_i (m_i cancels)

    const int key = keys[row];
    const int i1 = ((key >> 24) & 7) * 8 + ((key >> 16) & 7);
    const int i2 = i1 * 8 + ((key >> 8) & 7);
    const int i3 = i2 * 8 + (key & 7);
    const int C[3] = {h1[i1] - 1, h2[i2] - 1, h3[i3] - 1};
    const float T[3] = {T1, T2, T3};

    float vals[6];
    #pragma unroll
    for (int l = 0; l < 3; ++l) {
        const bool valid = C[l] > 0;
        const float pr = T[l] / fmaxf((float)C[l], 1.0f) - lg;
        vals[2 * l]     = valid ? pr : 0.0f;
        vals[2 * l + 1] = valid ? 1.0f : 0.0f;
    }

    __shared__ float red[4][6];
    #pragma unroll
    for (int s = 0; s < 6; ++s) {
        float v = vals[s];
        #pragma unroll
        for (int o = 32; o > 0; o >>= 1) v += __shfl_xor(v, o);
        vals[s] = v;
    }
    if (lane == 0)
        #pragma unroll
        for (int s = 0; s < 6; ++s) red[wid][s] = vals[s];
    __syncthreads();
    if (tid == 0) {
        #pragma unroll
        for (int s = 0; s < 6; ++s)
            blocksums[blockIdx.x * 8 + s] = red[0][s] + red[1][s] + red[2][s] + red[3][s];
    }
}

// ---------------------------------------------------------------------------
// final: sum 16 block results, run the 3-level scalar loop
// ---------------------------------------------------------------------------
__global__ void final_kernel(const float* __restrict__ blocksums, float* __restrict__ out)
{
    if (threadIdx.x != 0) return;
    float sums[6] = {0, 0, 0, 0, 0, 0};
    for (int b = 0; b < 16; ++b)
        for (int s = 0; s < 6; ++s) sums[s] += blocksums[b * 8 + s];

    const float pen[3] = {2.0f, 1.41421356237309515f, 1.25992104989487319f};
    float total = 0.0f, max_lower = -INFINITY;
    int seen = 0;
    for (int l = 0; l < 3; ++l) {
        const float nv   = sums[2 * l + 1];
        const bool  any  = nv > 0.0f;
        const float mean = sums[2 * l] / fmaxf(nv, 1.0f);
        const float raw  = -mean;                    // TAU/TAU_BASE == 1
        const float lvl  = fmaxf(max_lower, raw);
        if (any) {
            total += lvl * pen[l];
            max_lower = fmaxf(max_lower, lvl);
            seen++;
        }
    }
    out[0] = total / (float)(seen > 0 ? seen : 1);
}

// ---------------------------------------------------------------------------
extern "C" void kernel_launch(void* const* d_in, const int* in_sizes, int n_in,
                              void* d_out, int out_size, void* d_ws, size_t ws_size,
                              hipStream_t stream)
{
    const float* emb    = (const float*)d_in[0];
    const int*   labels = (const int*)d_in[1];
    float*       out    = (float*)d_out;
    char*        ws     = (char*)d_ws;

    // ws layout
    unsigned char* zq    = (unsigned char*)(ws);                // 4194304 B (fp8 superfrag)
    int*   keys     = (int*)(ws + 4194304);                     // 16384 B
    float* partials = (float*)(ws + 4210688);                   // 2097152 B (32 coltiles)
    float* bsums    = (float*)(ws + 6307840);                   // 512 B

    prep_kernel<<<NB / 4, 256, 0, stream>>>(emb, labels, zq, keys);
    simtile_kernel<<<528, 256, 0, stream>>>(zq, keys, partials);
    rowreduce_kernel<<<NB / 256, 256, 0, stream>>>(partials, keys, bsums);
    final_kernel<<<1, 64, 0, stream>>>(bsums, out);
}

// Round 21
// 49.983 us; speedup vs baseline: 1.0286x; 1.0286x over previous
//
#include <hip/hip_runtime.h>
#include <hip/hip_bf16.h>
#include <stdint.h>

#define NB 4096
#define ND 1024

typedef __attribute__((ext_vector_type(4))) float f32x4;
typedef __attribute__((ext_vector_type(2))) long i64x2;   // 16B = two fp8 MFMA operands

// ---------------------------------------------------------------------------
// prep: row-normalize, quantize to fp8 e4m3 (OCP), write SUPERFRAG-ORDERED zq,
// pack label key. (byte-identical to R14 -- passed, absmax 0.0)
// ---------------------------------------------------------------------------
__global__ __launch_bounds__(256) void prep_kernel(
    const float* __restrict__ emb, const int* __restrict__ labels,
    unsigned char* __restrict__ zq, int* __restrict__ keys)
{
    const int wid = threadIdx.x >> 6, lane = threadIdx.x & 63;
    const int row = blockIdx.x * 4 + wid;
    const float4* src = (const float4*)(emb + (size_t)row * ND) + lane * 4;
    float4 v[4];
    float ss = 0.0f;
    #pragma unroll
    for (int j = 0; j < 4; ++j) {
        v[j] = src[j];
        ss += v[j].x * v[j].x + v[j].y * v[j].y + v[j].z * v[j].z + v[j].w * v[j].w;
    }
    #pragma unroll
    for (int o = 1; o < 64; o <<= 1) ss += __shfl_xor(ss, o);
    const float inv = 1.0f / fmaxf(sqrtf(ss), 1e-12f);

    int p0 = 0, p1 = 0, p2 = 0, p3 = 0;
    p0 = __builtin_amdgcn_cvt_pk_fp8_f32(v[0].x * inv, v[0].y * inv, p0, false);
    p0 = __builtin_amdgcn_cvt_pk_fp8_f32(v[0].z * inv, v[0].w * inv, p0, true);
    p1 = __builtin_amdgcn_cvt_pk_fp8_f32(v[1].x * inv, v[1].y * inv, p1, false);
    p1 = __builtin_amdgcn_cvt_pk_fp8_f32(v[1].z * inv, v[1].w * inv, p1, true);
    p2 = __builtin_amdgcn_cvt_pk_fp8_f32(v[2].x * inv, v[2].y * inv, p2, false);
    p2 = __builtin_amdgcn_cvt_pk_fp8_f32(v[2].z * inv, v[2].w * inv, p2, true);
    p3 = __builtin_amdgcn_cvt_pk_fp8_f32(v[3].x * inv, v[3].y * inv, p3, false);
    p3 = __builtin_amdgcn_cvt_pk_fp8_f32(v[3].z * inv, v[3].w * inv, p3, true);

    const int sf  = (row >> 4) * 16 + (lane >> 2);
    const int sel = (lane >> 1) & 1;
    const int c0  = (lane & 1) * 2;
    const int L0  = (row & 15) + 16 * c0;
    unsigned char* d = zq + (size_t)sf * 1024;
    int2 w01; w01.x = p0; w01.y = p1;   // k+0..7  -> chunk c0
    int2 w23; w23.x = p2; w23.y = p3;   // k+8..15 -> chunk c0+1
    *(int2*)(d + L0 * 16 + sel * 8)        = w01;
    *(int2*)(d + (L0 + 16) * 16 + sel * 8) = w23;

    if (lane == 0) {
        const int* lr = labels + row * 4;
        keys[row] = ((lr[3] & 7) << 24) | ((lr[0] & 7) << 16) |
                    ((lr[1] & 7) << 8)  |  (lr[2] & 7);
    }
}

// ---------------------------------------------------------------------------
// simtile (R21): R14 byte-identical (best, 49.6 us, absmax 0.0) + T5
// s_setprio(1/0) around each 32-MFMA cluster. K-loop is barrier-free with
// 2 waves/SIMD drifting to different phases -- the regime where setprio
// measured +4-7% (m191) vs null in lockstep schedules (m190). Structural
// wall otherwise: ~4-5 cy per 64B line-touch per CU (R16/R17/R18/R20 all
// null against it); floor = 14 us loads + ~8 us MFMA ~= observed 28 us.
// ---------------------------------------------------------------------------
__global__ __launch_bounds__(256, 2) void simtile_kernel(
    const unsigned char* __restrict__ zq, const int* __restrict__ keys,
    float* __restrict__ partials)
{
    const int b = blockIdx.x;
    const int p = (b & 7) * 66 + (b >> 3);   // XCD-contiguous triangle index
    int r = (int)((sqrtf(8.0f * p + 1.0f) - 1.0f) * 0.5f);
    while ((r + 1) * (r + 2) / 2 <= p) ++r;
    while (r * (r + 1) / 2 > p) --r;
    const int bi = p - r * (r + 1) / 2;      // I panel (rows of D), bi <= bj
    const int bj = r;                        // J panel (cols of D)
    const int I0 = bi * 128, J0 = bj * 128;
    const bool offdiag = (bi != bj);
    const bool diag = !offdiag;

    const int tid = threadIdx.x;
    const int lane = tid & 63, w = tid >> 6;          // 4 waves
    const int llo = lane & 15, lhi = lane >> 4;
    const int wm = w >> 1, wn = w & 1;                // 2 x 2 wave grid

    __shared__ float epiA[2][128][4];                 // 4 KB
    __shared__ float epiB[2][128][4];                 // 4 KB
    __shared__ int keyI[128];
    __shared__ int keyJ[128];

    if (tid < 128) {
        keyI[tid] = keys[I0 + tid];
        keyJ[tid] = keys[J0 + tid];
    }

    // superfrag bases: rowtile stride 16KB (16 sf x 1KB); t64 stride 1KB
    const unsigned char* aF = zq + (size_t)(bi * 8 + wm * 4) * 16384 + lane * 16;
    const unsigned char* bF = zq + (size_t)(bj * 8 + wn * 4) * 16384 + lane * 16;

    f32x4 acc[4][4];
    #pragma unroll
    for (int m = 0; m < 4; ++m)
        #pragma unroll
        for (int n = 0; n < 4; ++n)
            acc[m][n] = (f32x4){0.f, 0.f, 0.f, 0.f};

    #define LOADF(A, Bf, T)                                                        \
        do {                                                                       \
            _Pragma("unroll")                                                      \
            for (int m = 0; m < 4; ++m)                                            \
                A[m] = *(const i64x2*)(aF + (size_t)(m) * 16384 + (T) * 1024);     \
            _Pragma("unroll")                                                      \
            for (int n = 0; n < 4; ++n)                                            \
                Bf[n] = *(const i64x2*)(bF + (size_t)(n) * 16384 + (T) * 1024);    \
        } while (0)

    #define STEP(A, Bf)                                                            \
        do {                                                                       \
            __builtin_amdgcn_s_setprio(1);                                         \
            _Pragma("unroll")                                                      \
            for (int m = 0; m < 4; ++m)                                            \
                _Pragma("unroll")                                                  \
                for (int n = 0; n < 4; ++n) {                                      \
                    acc[m][n] = __builtin_amdgcn_mfma_f32_16x16x32_fp8_fp8(        \
                        A[m][0], Bf[n][0], acc[m][n], 0, 0, 0);                    \
                    acc[m][n] = __builtin_amdgcn_mfma_f32_16x16x32_fp8_fp8(        \
                        A[m][1], Bf[n][1], acc[m][n], 0, 0, 0);                    \
                }                                                                  \
            __builtin_amdgcn_s_setprio(0);                                         \
        } while (0)

    {
        i64x2 aC[4], bC[4], aN[4], bN[4];
        LOADF(aC, bC, 0);
        #pragma unroll 1
        for (int t2 = 0; t2 < 8; ++t2) {               // 16 K-64 super-steps
            LOADF(aN, bN, 2 * t2 + 1);
            STEP(aC, bC);
            if (t2 < 7) LOADF(aC, bC, 2 * t2 + 2);
            STEP(aN, bN);
        }
    }
    #undef LOADF
    #undef STEP

    __syncthreads();   // keys visible; epi ready

    // -------- dual-sided epilogue ------------------------------------------
    int kJ[4], tcol[4];
    #pragma unroll
    for (int n = 0; n < 4; ++n) {
        tcol[n] = wn * 64 + n * 16 + llo;
        kJ[n] = keyJ[tcol[n]];
    }

    float stB[4][4];
    #pragma unroll
    for (int n = 0; n < 4; ++n)
        #pragma unroll
        for (int s = 0; s < 4; ++s) stB[n][s] = 0.0f;

    #pragma unroll
    for (int m = 0; m < 4; ++m) {
        float stA[4][4];
        #pragma unroll
        for (int rr = 0; rr < 4; ++rr)
            #pragma unroll
            for (int s = 0; s < 4; ++s) stA[rr][s] = 0.0f;

        int kI[4], trow[4];
        #pragma unroll
        for (int rr = 0; rr < 4; ++rr) {
            trow[rr] = wm * 64 + m * 16 + lhi * 4 + rr;
            kI[rr] = keyI[trow[rr]];
        }
        #pragma unroll
        for (int n = 0; n < 4; ++n) {
            #pragma unroll
            for (int rr = 0; rr < 4; ++rr) {
                const float v = acc[m][n][rr] * 10.0f;
                const int x = kI[rr] ^ kJ[n];
                const float pen = (x & 0xFF000000) ? 1.0f : 0.0f;
                const float g = __expf(v - 10.0f - pen);
                if (!(diag && trow[rr] == tcol[n])) {
                    stA[rr][0] += g;           stB[n][0] += g;
                    if ((x & 0xFFFF0000) == 0) { stA[rr][1] += v; stB[n][1] += v; }
                    if ((x & 0xFFFFFF00) == 0) { stA[rr][2] += v; stB[n][2] += v; }
                    if (x == 0)                { stA[rr][3] += v; stB[n][3] += v; }
                }
            }
        }
        // side A: reduce over the 16 llo lanes (cols within wave)
        #pragma unroll
        for (int rr = 0; rr < 4; ++rr)
            #pragma unroll
            for (int s = 0; s < 4; ++s) {
                float vv = stA[rr][s];
                vv += __shfl_xor(vv, 1);
                vv += __shfl_xor(vv, 2);
                vv += __shfl_xor(vv, 4);
                vv += __shfl_xor(vv, 8);
                stA[rr][s] = vv;
            }
        if (llo == 0) {
            #pragma unroll
            for (int rr = 0; rr < 4; ++rr) {
                float4 o; o.x = stA[rr][0]; o.y = stA[rr][1]; o.z = stA[rr][2]; o.w = stA[rr][3];
                *(float4*)&epiA[wn][trow[rr]][0] = o;
            }
        }
    }
    // side B: reduce over the 4 lhi lane-groups (rows within wave)
    #pragma unroll
    for (int n = 0; n < 4; ++n)
        #pragma unroll
        for (int s = 0; s < 4; ++s) {
            float vv = stB[n][s];
            vv += __shfl_xor(vv, 16);
            vv += __shfl_xor(vv, 32);
            stB[n][s] = vv;
        }
    if (lhi == 0) {
        #pragma unroll
        for (int n = 0; n < 4; ++n) {
            float4 o; o.x = stB[n][0]; o.y = stB[n][1]; o.z = stB[n][2]; o.w = stB[n][3];
            *(float4*)&epiB[wm][tcol[n]][0] = o;
        }
    }
    __syncthreads();

    if (tid < 128) {
        const float4 a0 = *(const float4*)&epiA[0][tid][0];
        const float4 a1 = *(const float4*)&epiA[1][tid][0];
        float4 o; o.x = a0.x + a1.x; o.y = a0.y + a1.y; o.z = a0.z + a1.z; o.w = a0.w + a1.w;
        *(float4*)(partials + ((size_t)bj * NB + I0 + tid) * 4) = o;
        if (offdiag) {
            const float4 b0 = *(const float4*)&epiB[0][tid][0];
            const float4 b1 = *(const float4*)&epiB[1][tid][0];
            float4 q; q.x = b0.x + b1.x; q.y = b0.y + b1.y; q.z = b0.z + b1.z; q.w = b0.w + b1.w;
            *(float4*)(partials + ((size_t)bi * NB + J0 + tid) * 4) = q;
        }
    }
}

// ---------------------------------------------------------------------------
// row reduce: block-local LDS histogram of keys (counts), then sum {G,T1,T2,T3}
// over 32 coltiles, per-level per-row values, block-reduce to 6 sums.
// ---------------------------------------------------------------------------
__global__ __launch_bounds__(256) void rowreduce_kernel(
    const float* __restrict__ partials, const int* __restrict__ keys,
    float* __restrict__ blocksums)
{
    const int tid = threadIdx.x;
    const int row = blockIdx.x * 256 + tid;
    const int lane = tid & 63, wid = tid >> 6;

    __shared__ int h3[4096];
    __shared__ int h2[512];
    __shared__ int h1[64];

    for (int i = tid; i < 4096; i += 256) h3[i] = 0;
    __syncthreads();
    for (int i = tid; i < 4096; i += 256) {
        const int k = keys[i];
        const int i3 = (((((k >> 24) & 7) * 8 + ((k >> 16) & 7)) * 8 + ((k >> 8) & 7)) * 8) + (k & 7);
        atomicAdd(&h3[i3], 1);
    }
    __syncthreads();
    for (int i = tid; i < 512; i += 256) {
        int s = 0;
        #pragma unroll
        for (int j = 0; j < 8; ++j) s += h3[i * 8 + j];
        h2[i] = s;
    }
    __syncthreads();
    if (tid < 64) {
        int s = 0;
        #pragma unroll
        for (int j = 0; j < 8; ++j) s += h2[tid * 8 + j];
        h1[tid] = s;
    }
    __syncthreads();

    float G = 0.f, T1 = 0.f, T2 = 0.f, T3 = 0.f;
    for (int ct = 0; ct < 32; ++ct) {
        const float4 u = *(const float4*)(partials + ((size_t)ct * NB + row) * 4);
        G += u.x; T1 += u.y; T2 += u.z; T3 += u.w;
    }
    const float lg = logf(fmaxf(G, 1e-30f)) + 10.0f;   // = logZ + m_i (m_i cancels)

    const int key = keys[row];
    const int i1 = ((key >> 24) & 7) * 8 + ((key >> 16) & 7);
    const int i2 = i1 * 8 + ((key >> 8) & 7);
    const int i3 = i2 * 8 + (key & 7);
    const int C[3] = {h1[i1] - 1, h2[i2] - 1, h3[i3] - 1};
    const float T[3] = {T1, T2, T3};

    float vals[6];
    #pragma unroll
    for (int l = 0; l < 3; ++l) {
        const bool valid = C[l] > 0;
        const float pr = T[l] / fmaxf((float)C[l], 1.0f) - lg;
        vals[2 * l]     = valid ? pr : 0.0f;
        vals[2 * l + 1] = valid ? 1.0f : 0.0f;
    }

    __shared__ float red[4][6];
    #pragma unroll
    for (int s = 0; s < 6; ++s) {
        float v = vals[s];
        #pragma unroll
        for (int o = 32; o > 0; o >>= 1) v += __shfl_xor(v, o);
        vals[s] = v;
    }
    if (lane == 0)
        #pragma unroll
        for (int s = 0; s < 6; ++s) red[wid][s] = vals[s];
    __syncthreads();
    if (tid == 0) {
        #pragma unroll
        for (int s = 0; s < 6; ++s)
            blocksums[blockIdx.x * 8 + s] = red[0][s] + red[1][s] + red[2][s] + red[3][s];
    }
}

// ---------------------------------------------------------------------------
// final: sum 16 block results, run the 3-level scalar loop
// ---------------------------------------------------------------------------
__global__ void final_kernel(const float* __restrict__ blocksums, float* __restrict__ out)
{
    if (threadIdx.x != 0) return;
    float sums[6] = {0, 0, 0, 0, 0, 0};
    for (int b = 0; b < 16; ++b)
        for (int s = 0; s < 6; ++s) sums[s] += blocksums[b * 8 + s];

    const float pen[3] = {2.0f, 1.41421356237309515f, 1.25992104989487319f};
    float total = 0.0f, max_lower = -INFINITY;
    int seen = 0;
    for (int l = 0; l < 3; ++l) {
        const float nv   = sums[2 * l + 1];
        const bool  any  = nv > 0.0f;
        const float mean = sums[2 * l] / fmaxf(nv, 1.0f);
        const float raw  = -mean;                    // TAU/TAU_BASE == 1
        const float lvl  = fmaxf(max_lower, raw);
        if (any) {
            total += lvl * pen[l];
            max_lower = fmaxf(max_lower, lvl);
            seen++;
        }
    }
    out[0] = total / (float)(seen > 0 ? seen : 1);
}

// ---------------------------------------------------------------------------
extern "C" void kernel_launch(void* const* d_in, const int* in_sizes, int n_in,
                              void* d_out, int out_size, void* d_ws, size_t ws_size,
                              hipStream_t stream)
{
    const float* emb    = (const float*)d_in[0];
    const int*   labels = (const int*)d_in[1];
    float*       out    = (float*)d_out;
    char*        ws     = (char*)d_ws;

    // ws layout
    unsigned char* zq    = (unsigned char*)(ws);                // 4194304 B (fp8 superfrag)
    int*   keys     = (int*)(ws + 4194304);                     // 16384 B
    float* partials = (float*)(ws + 4210688);                   // 2097152 B (32 coltiles)
    float* bsums    = (float*)(ws + 6307840);                   // 512 B

    prep_kernel<<<NB / 4, 256, 0, stream>>>(emb, labels, zq, keys);
    simtile_kernel<<<528, 256, 0, stream>>>(zq, keys, partials);
    rowreduce_kernel<<<NB / 256, 256, 0, stream>>>(partials, keys, bsums);
    final_kernel<<<1, 64, 0, stream>>>(bsums, out);
}